// Round 1
// baseline (983.778 us; speedup 1.0000x reference)
//
#include <hip/hip_runtime.h>

#define B_ 4
#define S_ 4096
#define D_ 2048
#define H_ 8192
#define KCAP 491
#define SLOTP 512
#define MPAD 2048  // B_ * SLOTP

typedef __attribute__((ext_vector_type(8))) short short8;
typedef __attribute__((ext_vector_type(4))) float float4_t;

__device__ __forceinline__ unsigned short f2bf(float f) {
    unsigned int u = __float_as_uint(f);
    unsigned int r = u + 0x7fffu + ((u >> 16) & 1u);
    return (unsigned short)(r >> 16);
}

__device__ __forceinline__ void gload_lds16(const void* g, void* l) {
    __builtin_amdgcn_global_load_lds((const __attribute__((address_space(1))) void*)g,
                                     (__attribute__((address_space(3))) void*)l, 16, 0, 0);
}

// ---------------- transpose + f32->bf16 cast: out[C][R] = cast(in[R][C]) ----------------
__global__ __launch_bounds__(256) void k_transpose_bf16(const float* __restrict__ in,
                                                        unsigned short* __restrict__ out,
                                                        int R, int C) {
    __shared__ float s[32][33];
    int tx = threadIdx.x & 31, ty = threadIdx.x >> 5;
    int r0 = blockIdx.x * 32, c0 = blockIdx.y * 32;
#pragma unroll
    for (int p = 0; p < 4; p++) {
        int r = ty + p * 8;
        s[r][tx] = in[(size_t)(r0 + r) * C + c0 + tx];
    }
    __syncthreads();
#pragma unroll
    for (int p = 0; p < 4; p++) {
        int r = ty + p * 8;
        out[(size_t)(c0 + r) * R + r0 + tx] = f2bf(s[tx][r]);
    }
}

// ---------------- router: logits = x.Wr, auxlog = x.Wa (f64 accumulate) ----------------
__global__ __launch_bounds__(256) void k_router(const float* __restrict__ x,
                                                const float* __restrict__ Wr,
                                                const float* __restrict__ Wa,
                                                float* __restrict__ logits,
                                                float* __restrict__ auxlog) {
    int w = threadIdx.x >> 6, lane = threadIdx.x & 63;
    int row = blockIdx.x * 4 + w;
    const float* xr = x + (size_t)row * D_;
    double sr = 0.0, sa = 0.0;
#pragma unroll
    for (int it = 0; it < 8; it++) {
        int off = it * 256 + lane * 4;
        float4 xv = *(const float4*)(xr + off);
        float4 rv = *(const float4*)(Wr + off);
        float4 av = *(const float4*)(Wa + off);
        sr += (double)xv.x * rv.x + (double)xv.y * rv.y + (double)xv.z * rv.z + (double)xv.w * rv.w;
        sa += (double)xv.x * av.x + (double)xv.y * av.y + (double)xv.z * av.z + (double)xv.w * av.w;
    }
#pragma unroll
    for (int off = 32; off > 0; off >>= 1) {
        sr += __shfl_down(sr, off);
        sa += __shfl_down(sa, off);
    }
    if (lane == 0) {
        logits[row] = (float)sr;
        auxlog[row] = (float)sa;
    }
}

// ---------------- per-batch top-k via bitonic sort of (value, 4095-idx) keys ----------------
__global__ __launch_bounds__(1024) void k_topk(const float* __restrict__ logits,
                                               int* __restrict__ sel, float* __restrict__ rw,
                                               int* __restrict__ flags) {
    __shared__ unsigned long long keys[S_];
    __shared__ int sarr[SLOTP];
    int b = blockIdx.x, tid = threadIdx.x;
    const float* lg = logits + (size_t)b * S_;
    for (int i = tid; i < S_; i += 1024) {
        unsigned u = __float_as_uint(lg[i]);
        u = (u & 0x80000000u) ? ~u : (u | 0x80000000u);
        keys[i] = ((unsigned long long)u << 32) | (unsigned)(S_ - 1 - i);
    }
    __syncthreads();
    for (int k = 2; k <= S_; k <<= 1) {
        for (int j = k >> 1; j > 0; j >>= 1) {
            for (int s = tid; s < S_ / 2; s += 1024) {
                int i = 2 * s - (s & (j - 1));
                int ixj = i | j;
                bool up = ((i & k) == 0);
                unsigned long long a = keys[i], c = keys[ixj];
                if ((a < c) == up) { keys[i] = c; keys[ixj] = a; }  // descending sort
            }
            __syncthreads();
        }
    }
    if (tid < KCAP) sarr[tid] = (int)(S_ - 1 - (unsigned)(keys[tid] & 0xFFFFFFFFull));
    __syncthreads();
    if (tid < KCAP) {
        int s = sarr[tid];
        int rank = 0;
        for (int j = 0; j < KCAP; j++) rank += (sarr[j] < s) ? 1 : 0;
        sel[b * SLOTP + rank] = s;
        rw[b * SLOTP + rank] = lg[s];
        flags[s] = 1;
    } else if (tid < SLOTP) {
        sel[b * SLOTP + tid] = 0;
        rw[b * SLOTP + tid] = 0.f;
    }
}

// ---------------- gather selected tokens -> bf16 A [MPAD][D_] ----------------
__global__ __launch_bounds__(256) void k_gather(const float* __restrict__ x,
                                                const int* __restrict__ sel,
                                                unsigned short* __restrict__ Abuf) {
    int row = blockIdx.x;
    int b = row >> 9, slot = row & 511;
    int tid = threadIdx.x;
    unsigned short* dst = Abuf + (size_t)row * D_ + tid * 8;
    if (slot < KCAP) {
        int tok = sel[b * SLOTP + slot];
        const float* src = x + ((size_t)(b * S_ + tok)) * D_ + tid * 8;
        float4 v0 = *(const float4*)(src);
        float4 v1 = *(const float4*)(src + 4);
        union { unsigned short us[8]; uint4 v; } pk;
        pk.us[0] = f2bf(v0.x); pk.us[1] = f2bf(v0.y); pk.us[2] = f2bf(v0.z); pk.us[3] = f2bf(v0.w);
        pk.us[4] = f2bf(v1.x); pk.us[5] = f2bf(v1.y); pk.us[6] = f2bf(v1.z); pk.us[7] = f2bf(v1.w);
        *(uint4*)dst = pk.v;
    } else {
        *(uint4*)dst = make_uint4(0u, 0u, 0u, 0u);
    }
}

// ---------------- out = x (float4 copy) ----------------
__global__ __launch_bounds__(256) void k_copy(const float4* __restrict__ in,
                                              float4* __restrict__ out, int n4) {
    int i = blockIdx.x * blockDim.x + threadIdx.x;
    int stride = gridDim.x * blockDim.x;
    for (; i < n4; i += stride) out[i] = in[i];
}

// ---------------- fused dual GEMM1: h = silu(A@W1) * (A@W3), bf16 out ----------------
__global__ __launch_bounds__(256) void k_gemm1(const unsigned short* __restrict__ A,
                                               const unsigned short* __restrict__ B1,
                                               const unsigned short* __restrict__ B2,
                                               unsigned short* __restrict__ Hbuf) {
    __shared__ unsigned short sA[128 * 32];
    __shared__ unsigned short sB1[128 * 32];
    __shared__ unsigned short sB2[128 * 32];
    const int tid = threadIdx.x;
    const int w = tid >> 6, lane = tid & 63;
    const int m0 = blockIdx.x * 128, n0 = blockIdx.y * 128;
    const int wm = (w >> 1) * 64, wn = (w & 1) * 64;
    const int srow = lane >> 2, skc = (lane & 3) * 8;
    const int lrow = lane & 15, lk = (lane >> 4) * 8;
    float4_t acc1[4][4] = {};
    float4_t acc2[4][4] = {};

    for (int k0 = 0; k0 < D_; k0 += 32) {
#pragma unroll
        for (int q = 0; q < 6; q++) {
            int c = w * 6 + q;  // 0..23: 8 chunks A, 8 B1, 8 B2
            int sub = c & 7;
            int row = sub * 16 + srow;
            if (c < 8)
                gload_lds16(A + (size_t)(m0 + row) * D_ + k0 + skc, sA + sub * 512);
            else if (c < 16)
                gload_lds16(B1 + (size_t)(n0 + row) * D_ + k0 + skc, sB1 + sub * 512);
            else
                gload_lds16(B2 + (size_t)(n0 + row) * D_ + k0 + skc, sB2 + sub * 512);
        }
        __builtin_amdgcn_s_waitcnt(0);
        __syncthreads();
        short8 af[4];
#pragma unroll
        for (int i = 0; i < 4; i++)
            af[i] = *(const short8*)(sA + (wm + i * 16 + lrow) * 32 + lk);
#pragma unroll
        for (int j = 0; j < 4; j++) {
            short8 bf1 = *(const short8*)(sB1 + (wn + j * 16 + lrow) * 32 + lk);
            short8 bf2 = *(const short8*)(sB2 + (wn + j * 16 + lrow) * 32 + lk);
#pragma unroll
            for (int i = 0; i < 4; i++) {
                acc1[i][j] = __builtin_amdgcn_mfma_f32_16x16x32_bf16(af[i], bf1, acc1[i][j], 0, 0, 0);
                acc2[i][j] = __builtin_amdgcn_mfma_f32_16x16x32_bf16(af[i], bf2, acc2[i][j], 0, 0, 0);
            }
        }
        __syncthreads();
    }
#pragma unroll
    for (int i = 0; i < 4; i++) {
#pragma unroll
        for (int j = 0; j < 4; j++) {
            int n = n0 + wn + j * 16 + lrow;
#pragma unroll
            for (int r = 0; r < 4; r++) {
                int m = m0 + wm + i * 16 + (lane >> 4) * 4 + r;
                float g1 = acc1[i][j][r];
                float g2 = acc2[i][j][r];
                float hv = (g1 / (1.f + expf(-g1))) * g2;
                Hbuf[(size_t)m * H_ + n] = f2bf(hv);
            }
        }
    }
}

// ---------------- GEMM2: y = h @ W2, scatter out[b,sel[slot],:] += rw*y ----------------
__global__ __launch_bounds__(256) void k_gemm2(const unsigned short* __restrict__ A,
                                               const unsigned short* __restrict__ Bt,
                                               const int* __restrict__ sel,
                                               const float* __restrict__ rw,
                                               float* __restrict__ out) {
    __shared__ unsigned short sA[128 * 32];
    __shared__ unsigned short sB[128 * 32];
    const int tid = threadIdx.x;
    const int w = tid >> 6, lane = tid & 63;
    const int m0 = blockIdx.x * 128, n0 = blockIdx.y * 128;
    const int wm = (w >> 1) * 64, wn = (w & 1) * 64;
    const int srow = lane >> 2, skc = (lane & 3) * 8;
    const int lrow = lane & 15, lk = (lane >> 4) * 8;
    float4_t acc[4][4] = {};

    for (int k0 = 0; k0 < H_; k0 += 32) {
#pragma unroll
        for (int q = 0; q < 4; q++) {
            int c = w * 4 + q;  // 0..15: 8 chunks A, 8 B
            int sub = c & 7;
            int row = sub * 16 + srow;
            if (c < 8)
                gload_lds16(A + (size_t)(m0 + row) * H_ + k0 + skc, sA + sub * 512);
            else
                gload_lds16(Bt + (size_t)(n0 + row) * H_ + k0 + skc, sB + sub * 512);
        }
        __builtin_amdgcn_s_waitcnt(0);
        __syncthreads();
        short8 af[4];
#pragma unroll
        for (int i = 0; i < 4; i++)
            af[i] = *(const short8*)(sA + (wm + i * 16 + lrow) * 32 + lk);
#pragma unroll
        for (int j = 0; j < 4; j++) {
            short8 bf = *(const short8*)(sB + (wn + j * 16 + lrow) * 32 + lk);
#pragma unroll
            for (int i = 0; i < 4; i++)
                acc[i][j] = __builtin_amdgcn_mfma_f32_16x16x32_bf16(af[i], bf, acc[i][j], 0, 0, 0);
        }
        __syncthreads();
    }
#pragma unroll
    for (int i = 0; i < 4; i++) {
#pragma unroll
        for (int r = 0; r < 4; r++) {
            int m = m0 + wm + i * 16 + (lane >> 4) * 4 + r;
            int b = m >> 9, slot = m & 511;
            if (slot < KCAP) {
                int tok = sel[b * SLOTP + slot];
                float wgt = rw[b * SLOTP + slot];
                float* orow = out + ((size_t)(b * S_ + tok)) * D_;
#pragma unroll
                for (int j = 0; j < 4; j++) {
                    int n = n0 + wn + j * 16 + lrow;
                    orow[n] += wgt * acc[i][j][r];
                }
            }
        }
    }
}

// ---------------- aux BCE loss (reproduces reference's tgt-indexing quirk) ----------------
__global__ __launch_bounds__(256) void k_aux(const float* __restrict__ auxlog,
                                             const int* __restrict__ flags,
                                             float* __restrict__ auxout) {
    int i = blockIdx.x * 256 + threadIdx.x;
    float z = auxlog[i];
    float p = 1.f / (1.f + expf(-z));
    p = fminf(fmaxf(p, 1e-7f), 1.f - 1e-7f);
    int tgt = (i < S_) ? flags[i] : 0;
    float term = tgt ? logf(p) : log1pf(-p);
#pragma unroll
    for (int off = 32; off > 0; off >>= 1) term += __shfl_down(term, off);
    __shared__ float red[4];
    int w = threadIdx.x >> 6, lane = threadIdx.x & 63;
    if (lane == 0) red[w] = term;
    __syncthreads();
    if (threadIdx.x == 0) {
        float s = red[0] + red[1] + red[2] + red[3];
        atomicAdd(auxout, -s * (1.f / 16384.f));
    }
}

extern "C" void kernel_launch(void* const* d_in, const int* in_sizes, int n_in,
                              void* d_out, int out_size, void* d_ws, size_t ws_size,
                              hipStream_t stream) {
    const float* x  = (const float*)d_in[0];
    const float* Wr = (const float*)d_in[1];
    const float* Wa = (const float*)d_in[2];
    const float* W1 = (const float*)d_in[3];
    const float* W2 = (const float*)d_in[4];  // note dict order: W2 before W3
    const float* W3 = (const float*)d_in[5];
    float* out = (float*)d_out;

    char* ws = (char*)d_ws;
    // layout (bytes):
    unsigned short* WTa  = (unsigned short*)(ws);                // 32MB: W1t, later reused for W2t
    unsigned short* WTb  = (unsigned short*)(ws + 33554432ull);  // 32MB: W3t
    unsigned short* Abuf = (unsigned short*)(ws + 67108864ull);  // 8MB:  gathered tokens bf16
    unsigned short* Hbuf = (unsigned short*)(ws + 75497472ull);  // 32MB: SwiGLU hidden bf16
    float* logits = (float*)(ws + 109051904ull);                 // 64KB
    float* auxlog = (float*)(ws + 109117440ull);                 // 64KB
    int*   sel    = (int*)(ws + 109182976ull);                   // 8KB
    float* rwbuf  = (float*)(ws + 109191168ull);                 // 8KB
    int*   flags  = (int*)(ws + 109199360ull);                   // 16KB
    if (ws_size < 109215744ull) return;  // insufficient scratch: fail cleanly

    hipMemsetAsync(flags, 0, S_ * sizeof(int), stream);
    hipMemsetAsync(out + (size_t)B_ * S_ * D_, 0, sizeof(float), stream);

    k_transpose_bf16<<<dim3(D_ / 32, H_ / 32), 256, 0, stream>>>(W1, WTa, D_, H_);
    k_transpose_bf16<<<dim3(D_ / 32, H_ / 32), 256, 0, stream>>>(W3, WTb, D_, H_);
    k_router<<<4096, 256, 0, stream>>>(x, Wr, Wa, logits, auxlog);
    k_topk<<<4, 1024, 0, stream>>>(logits, sel, rwbuf, flags);
    k_gather<<<MPAD, 256, 0, stream>>>(x, sel, Abuf);
    k_copy<<<4096, 256, 0, stream>>>((const float4*)x, (float4*)out, B_ * S_ * D_ / 4);
    k_gemm1<<<dim3(MPAD / 128, H_ / 128), 256, 0, stream>>>(Abuf, WTa, WTb, Hbuf);
    k_transpose_bf16<<<dim3(H_ / 32, D_ / 32), 256, 0, stream>>>(W2, WTa, H_, D_);
    k_gemm2<<<dim3(MPAD / 128, D_ / 128), 256, 0, stream>>>(Hbuf, WTa, sel, rwbuf, out);
    k_aux<<<64, 256, 0, stream>>>(auxlog, flags, out + (size_t)B_ * S_ * D_);
}

// Round 2
// 763.639 us; speedup vs baseline: 1.2883x; 1.2883x over previous
//
#include <hip/hip_runtime.h>

#define B_ 4
#define S_ 4096
#define D_ 2048
#define H_ 8192
#define KCAP 491
#define SLOTP 512
#define MPAD 2048  // B_ * SLOTP

typedef __attribute__((ext_vector_type(8))) short short8;
typedef __attribute__((ext_vector_type(4))) float float4_t;

__device__ __forceinline__ unsigned short f2bf(float f) {
    unsigned int u = __float_as_uint(f);
    unsigned int r = u + 0x7fffu + ((u >> 16) & 1u);
    return (unsigned short)(r >> 16);
}

__device__ __forceinline__ void gload_lds16(const void* g, void* l) {
    __builtin_amdgcn_global_load_lds((const __attribute__((address_space(1))) void*)g,
                                     (__attribute__((address_space(3))) void*)l, 16, 0, 0);
}

// ---------------- transpose + f32->bf16 cast: out[C][R] = cast(in[R][C]) ----------------
// 64x64 tiles, float4 loads, ushort4 stores.
__global__ __launch_bounds__(256) void k_transpose_bf16(const float* __restrict__ in,
                                                        unsigned short* __restrict__ out,
                                                        int R, int C) {
    __shared__ float s[64][65];
    int t = threadIdx.x;
    int tx = t & 15, ty = t >> 4;  // tx: 4-col group / 4-row group, ty: 0..15
    int r0 = blockIdx.x * 64, c0 = blockIdx.y * 64;
#pragma unroll
    for (int q = 0; q < 4; q++) {
        int r = ty + q * 16;
        float4 v = *(const float4*)(in + (size_t)(r0 + r) * C + c0 + tx * 4);
        s[r][tx * 4 + 0] = v.x;
        s[r][tx * 4 + 1] = v.y;
        s[r][tx * 4 + 2] = v.z;
        s[r][tx * 4 + 3] = v.w;
    }
    __syncthreads();
#pragma unroll
    for (int q = 0; q < 4; q++) {
        int c = ty + q * 16;
        ushort4 o;
        o.x = f2bf(s[tx * 4 + 0][c]);
        o.y = f2bf(s[tx * 4 + 1][c]);
        o.z = f2bf(s[tx * 4 + 2][c]);
        o.w = f2bf(s[tx * 4 + 3][c]);
        *(ushort4*)(out + (size_t)(c0 + c) * R + r0 + tx * 4) = o;
    }
}

// ---------------- fused: out = x copy + router logits (f64 accum) ----------------
__global__ __launch_bounds__(256) void k_router_copy(const float* __restrict__ x,
                                                     const float* __restrict__ Wr,
                                                     const float* __restrict__ Wa,
                                                     float* __restrict__ out,
                                                     float* __restrict__ logits,
                                                     float* __restrict__ auxlog) {
    int w = threadIdx.x >> 6, lane = threadIdx.x & 63;
    int row = blockIdx.x * 4 + w;
    const float* xr = x + (size_t)row * D_;
    float* orow = out + (size_t)row * D_;
    double sr = 0.0, sa = 0.0;
#pragma unroll
    for (int it = 0; it < 8; it++) {
        int off = it * 256 + lane * 4;
        float4 xv = *(const float4*)(xr + off);
        float4 rv = *(const float4*)(Wr + off);
        float4 av = *(const float4*)(Wa + off);
        *(float4*)(orow + off) = xv;
        sr += (double)xv.x * rv.x + (double)xv.y * rv.y + (double)xv.z * rv.z + (double)xv.w * rv.w;
        sa += (double)xv.x * av.x + (double)xv.y * av.y + (double)xv.z * av.z + (double)xv.w * av.w;
    }
#pragma unroll
    for (int off = 32; off > 0; off >>= 1) {
        sr += __shfl_down(sr, off);
        sa += __shfl_down(sa, off);
    }
    if (lane == 0) {
        logits[row] = (float)sr;
        auxlog[row] = (float)sa;
    }
}

// ---------------- per-batch top-k via bitonic sort of (value, 4095-idx) keys ----------------
__global__ __launch_bounds__(1024) void k_topk(const float* __restrict__ logits,
                                               int* __restrict__ sel, float* __restrict__ rw,
                                               int* __restrict__ flags) {
    __shared__ unsigned long long keys[S_];
    __shared__ int sarr[SLOTP];
    int b = blockIdx.x, tid = threadIdx.x;
    const float* lg = logits + (size_t)b * S_;
    for (int i = tid; i < S_; i += 1024) {
        unsigned u = __float_as_uint(lg[i]);
        u = (u & 0x80000000u) ? ~u : (u | 0x80000000u);
        keys[i] = ((unsigned long long)u << 32) | (unsigned)(S_ - 1 - i);
    }
    __syncthreads();
    for (int k = 2; k <= S_; k <<= 1) {
        for (int j = k >> 1; j > 0; j >>= 1) {
            for (int s = tid; s < S_ / 2; s += 1024) {
                int i = 2 * s - (s & (j - 1));
                int ixj = i | j;
                bool up = ((i & k) == 0);
                unsigned long long a = keys[i], c = keys[ixj];
                if ((a < c) == up) { keys[i] = c; keys[ixj] = a; }  // descending
            }
            __syncthreads();
        }
    }
    if (tid < KCAP) sarr[tid] = (int)(S_ - 1 - (unsigned)(keys[tid] & 0xFFFFFFFFull));
    __syncthreads();
    if (tid < KCAP) {
        int s = sarr[tid];
        int rank = 0;
        for (int j = 0; j < KCAP; j++) rank += (sarr[j] < s) ? 1 : 0;
        sel[b * SLOTP + rank] = s;
        rw[b * SLOTP + rank] = lg[s];
        flags[s] = 1;
    } else if (tid < SLOTP) {
        sel[b * SLOTP + tid] = 0;
        rw[b * SLOTP + tid] = 0.f;
    }
}

// ---------------- gather selected tokens -> bf16 A [MPAD][D_] ----------------
__global__ __launch_bounds__(256) void k_gather(const float* __restrict__ x,
                                                const int* __restrict__ sel,
                                                unsigned short* __restrict__ Abuf) {
    int row = blockIdx.x;
    int b = row >> 9, slot = row & 511;
    int tid = threadIdx.x;
    unsigned short* dst = Abuf + (size_t)row * D_ + tid * 8;
    if (slot < KCAP) {
        int tok = sel[b * SLOTP + slot];
        const float* src = x + ((size_t)(b * S_ + tok)) * D_ + tid * 8;
        float4 v0 = *(const float4*)(src);
        float4 v1 = *(const float4*)(src + 4);
        union { unsigned short us[8]; uint4 v; } pk;
        pk.us[0] = f2bf(v0.x); pk.us[1] = f2bf(v0.y); pk.us[2] = f2bf(v0.z); pk.us[3] = f2bf(v0.w);
        pk.us[4] = f2bf(v1.x); pk.us[5] = f2bf(v1.y); pk.us[6] = f2bf(v1.z); pk.us[7] = f2bf(v1.w);
        *(uint4*)dst = pk.v;
    } else {
        *(uint4*)dst = make_uint4(0u, 0u, 0u, 0u);
    }
}

// ---------------- fused dual GEMM1: h = silu(A@W1) * (A@W3), bf16 out ----------------
// Tile 128M x 64N, 4 waves, each wave 64x32 dual-output (acc = 64 regs total).
__global__ __launch_bounds__(256, 3) void k_gemm1(const unsigned short* __restrict__ A,
                                                  const unsigned short* __restrict__ B1,
                                                  const unsigned short* __restrict__ B2,
                                                  unsigned short* __restrict__ Hbuf) {
    __shared__ unsigned short sA[128 * 32];   // 8KB
    __shared__ unsigned short sB1[64 * 32];   // 4KB
    __shared__ unsigned short sB2[64 * 32];   // 4KB
    const int tid = threadIdx.x;
    const int w = tid >> 6, lane = tid & 63;
    const int m0 = blockIdx.x * 128, n0 = blockIdx.y * 64;
    const int wm = (w >> 1) * 64, wn = (w & 1) * 32;
    const int srow = lane >> 2, skc = (lane & 3) * 8;
    const int lrow = lane & 15, lk = (lane >> 4) * 8;
    float4_t acc1[4][2] = {};
    float4_t acc2[4][2] = {};

    for (int k0 = 0; k0 < D_; k0 += 32) {
#pragma unroll
        for (int q = 0; q < 4; q++) {
            int c = w * 4 + q;  // 0..15: 8 chunks A, 4 B1, 4 B2
            if (c < 8) {
                int row = c * 16 + srow;
                gload_lds16(A + (size_t)(m0 + row) * D_ + k0 + skc, sA + c * 512);
            } else if (c < 12) {
                int s = c - 8, row = s * 16 + srow;
                gload_lds16(B1 + (size_t)(n0 + row) * D_ + k0 + skc, sB1 + s * 512);
            } else {
                int s = c - 12, row = s * 16 + srow;
                gload_lds16(B2 + (size_t)(n0 + row) * D_ + k0 + skc, sB2 + s * 512);
            }
        }
        __builtin_amdgcn_s_waitcnt(0);
        __syncthreads();
        short8 af[4];
#pragma unroll
        for (int i = 0; i < 4; i++)
            af[i] = *(const short8*)(sA + (wm + i * 16 + lrow) * 32 + lk);
#pragma unroll
        for (int j = 0; j < 2; j++) {
            short8 bf1 = *(const short8*)(sB1 + (wn + j * 16 + lrow) * 32 + lk);
            short8 bf2 = *(const short8*)(sB2 + (wn + j * 16 + lrow) * 32 + lk);
#pragma unroll
            for (int i = 0; i < 4; i++) {
                acc1[i][j] = __builtin_amdgcn_mfma_f32_16x16x32_bf16(af[i], bf1, acc1[i][j], 0, 0, 0);
                acc2[i][j] = __builtin_amdgcn_mfma_f32_16x16x32_bf16(af[i], bf2, acc2[i][j], 0, 0, 0);
            }
        }
        __syncthreads();
    }
#pragma unroll
    for (int i = 0; i < 4; i++) {
#pragma unroll
        for (int j = 0; j < 2; j++) {
            int n = n0 + wn + j * 16 + lrow;
#pragma unroll
            for (int r = 0; r < 4; r++) {
                int m = m0 + wm + i * 16 + (lane >> 4) * 4 + r;
                float g1 = acc1[i][j][r];
                float g2 = acc2[i][j][r];
                float hv = (g1 / (1.f + expf(-g1))) * g2;
                Hbuf[(size_t)m * H_ + n] = f2bf(hv);
            }
        }
    }
}

// ---------------- GEMM2 split-K: y = h @ W2, atomic scatter out += rw*y ----------------
__global__ __launch_bounds__(256, 3) void k_gemm2(const unsigned short* __restrict__ A,
                                                  const unsigned short* __restrict__ Bt,
                                                  const int* __restrict__ sel,
                                                  const float* __restrict__ rw,
                                                  float* __restrict__ out) {
    __shared__ unsigned short sA[128 * 32];
    __shared__ unsigned short sB[128 * 32];
    const int tid = threadIdx.x;
    const int w = tid >> 6, lane = tid & 63;
    const int m0 = blockIdx.x * 128, n0 = blockIdx.y * 128;
    const int kbeg = blockIdx.z * (H_ / 4), kend = kbeg + H_ / 4;
    const int wm = (w >> 1) * 64, wn = (w & 1) * 64;
    const int srow = lane >> 2, skc = (lane & 3) * 8;
    const int lrow = lane & 15, lk = (lane >> 4) * 8;
    float4_t acc[4][4] = {};

    for (int k0 = kbeg; k0 < kend; k0 += 32) {
#pragma unroll
        for (int q = 0; q < 4; q++) {
            int c = w * 4 + q;  // 0..15: 8 chunks A, 8 B
            int sub = c & 7;
            int row = sub * 16 + srow;
            if (c < 8)
                gload_lds16(A + (size_t)(m0 + row) * H_ + k0 + skc, sA + sub * 512);
            else
                gload_lds16(Bt + (size_t)(n0 + row) * H_ + k0 + skc, sB + sub * 512);
        }
        __builtin_amdgcn_s_waitcnt(0);
        __syncthreads();
        short8 af[4];
#pragma unroll
        for (int i = 0; i < 4; i++)
            af[i] = *(const short8*)(sA + (wm + i * 16 + lrow) * 32 + lk);
#pragma unroll
        for (int j = 0; j < 4; j++) {
            short8 bf = *(const short8*)(sB + (wn + j * 16 + lrow) * 32 + lk);
#pragma unroll
            for (int i = 0; i < 4; i++)
                acc[i][j] = __builtin_amdgcn_mfma_f32_16x16x32_bf16(af[i], bf, acc[i][j], 0, 0, 0);
        }
        __syncthreads();
    }
#pragma unroll
    for (int i = 0; i < 4; i++) {
#pragma unroll
        for (int r = 0; r < 4; r++) {
            int m = m0 + wm + i * 16 + (lane >> 4) * 4 + r;
            int b = m >> 9, slot = m & 511;
            if (slot < KCAP) {
                int tok = sel[b * SLOTP + slot];
                float wgt = rw[b * SLOTP + slot];
                float* orow = out + ((size_t)(b * S_ + tok)) * D_;
#pragma unroll
                for (int j = 0; j < 4; j++) {
                    int n = n0 + wn + j * 16 + lrow;
                    atomicAdd(orow + n, wgt * acc[i][j][r]);
                }
            }
        }
    }
}

// ---------------- aux BCE loss (reproduces reference's tgt-indexing quirk) ----------------
__global__ __launch_bounds__(256) void k_aux(const float* __restrict__ auxlog,
                                             const int* __restrict__ flags,
                                             float* __restrict__ auxout) {
    int i = blockIdx.x * 256 + threadIdx.x;
    float z = auxlog[i];
    float p = 1.f / (1.f + expf(-z));
    p = fminf(fmaxf(p, 1e-7f), 1.f - 1e-7f);
    int tgt = (i < S_) ? flags[i] : 0;
    float term = tgt ? logf(p) : log1pf(-p);
#pragma unroll
    for (int off = 32; off > 0; off >>= 1) term += __shfl_down(term, off);
    __shared__ float red[4];
    int w = threadIdx.x >> 6, lane = threadIdx.x & 63;
    if (lane == 0) red[w] = term;
    __syncthreads();
    if (threadIdx.x == 0) {
        float s = red[0] + red[1] + red[2] + red[3];
        atomicAdd(auxout, -s * (1.f / 16384.f));
    }
}

extern "C" void kernel_launch(void* const* d_in, const int* in_sizes, int n_in,
                              void* d_out, int out_size, void* d_ws, size_t ws_size,
                              hipStream_t stream) {
    const float* x  = (const float*)d_in[0];
    const float* Wr = (const float*)d_in[1];
    const float* Wa = (const float*)d_in[2];
    const float* W1 = (const float*)d_in[3];
    const float* W2 = (const float*)d_in[4];  // dict order: W2 before W3
    const float* W3 = (const float*)d_in[5];
    float* out = (float*)d_out;

    char* ws = (char*)d_ws;
    unsigned short* WTa  = (unsigned short*)(ws);                // 32MB: W1t, later reused for W2t
    unsigned short* WTb  = (unsigned short*)(ws + 33554432ull);  // 32MB: W3t
    unsigned short* Abuf = (unsigned short*)(ws + 67108864ull);  // 8MB:  gathered tokens bf16
    unsigned short* Hbuf = (unsigned short*)(ws + 75497472ull);  // 32MB: SwiGLU hidden bf16
    float* logits = (float*)(ws + 109051904ull);                 // 64KB
    float* auxlog = (float*)(ws + 109117440ull);                 // 64KB
    int*   sel    = (int*)(ws + 109182976ull);                   // 8KB
    float* rwbuf  = (float*)(ws + 109191168ull);                 // 8KB
    int*   flags  = (int*)(ws + 109199360ull);                   // 16KB
    if (ws_size < 109215744ull) return;

    hipMemsetAsync(flags, 0, S_ * sizeof(int), stream);
    hipMemsetAsync(out + (size_t)B_ * S_ * D_, 0, sizeof(float), stream);

    k_transpose_bf16<<<dim3(D_ / 64, H_ / 64), 256, 0, stream>>>(W1, WTa, D_, H_);
    k_transpose_bf16<<<dim3(D_ / 64, H_ / 64), 256, 0, stream>>>(W3, WTb, D_, H_);
    k_router_copy<<<4096, 256, 0, stream>>>(x, Wr, Wa, out, logits, auxlog);
    k_topk<<<4, 1024, 0, stream>>>(logits, sel, rwbuf, flags);
    k_gather<<<MPAD, 256, 0, stream>>>(x, sel, Abuf);
    k_gemm1<<<dim3(MPAD / 128, H_ / 64), 256, 0, stream>>>(Abuf, WTa, WTb, Hbuf);
    k_transpose_bf16<<<dim3(H_ / 64, D_ / 64), 256, 0, stream>>>(W2, WTa, H_, D_);
    k_gemm2<<<dim3(MPAD / 128, D_ / 128, 4), 256, 0, stream>>>(Hbuf, WTa, sel, rwbuf, out);
    k_aux<<<64, 256, 0, stream>>>(auxlog, flags, out + (size_t)B_ * S_ * D_);
}

// Round 3
// 712.569 us; speedup vs baseline: 1.3806x; 1.0717x over previous
//
#include <hip/hip_runtime.h>

#define B_ 4
#define S_ 4096
#define D_ 2048
#define H_ 8192
#define KCAP 491
#define SLOTP 512
#define MPAD 2048  // B_ * SLOTP

typedef __attribute__((ext_vector_type(8))) short short8;
typedef __attribute__((ext_vector_type(4))) float float4_t;

__device__ __forceinline__ unsigned short f2bf(float f) {
    unsigned int u = __float_as_uint(f);
    unsigned int r = u + 0x7fffu + ((u >> 16) & 1u);
    return (unsigned short)(r >> 16);
}

__device__ __forceinline__ void gload_lds16(const void* g, void* l) {
    __builtin_amdgcn_global_load_lds((const __attribute__((address_space(1))) void*)g,
                                     (__attribute__((address_space(3))) void*)l, 16, 0, 0);
}

// ---------------- transpose + f32->bf16 cast: out[C][R] = cast(in[R][C]) ----------------
__global__ __launch_bounds__(256) void k_transpose_bf16(const float* __restrict__ in,
                                                        unsigned short* __restrict__ out,
                                                        int R, int C) {
    __shared__ float s[64][65];
    int t = threadIdx.x;
    int tx = t & 15, ty = t >> 4;
    int r0 = blockIdx.x * 64, c0 = blockIdx.y * 64;
#pragma unroll
    for (int q = 0; q < 4; q++) {
        int r = ty + q * 16;
        float4 v = *(const float4*)(in + (size_t)(r0 + r) * C + c0 + tx * 4);
        s[r][tx * 4 + 0] = v.x;
        s[r][tx * 4 + 1] = v.y;
        s[r][tx * 4 + 2] = v.z;
        s[r][tx * 4 + 3] = v.w;
    }
    __syncthreads();
#pragma unroll
    for (int q = 0; q < 4; q++) {
        int c = ty + q * 16;
        ushort4 o;
        o.x = f2bf(s[tx * 4 + 0][c]);
        o.y = f2bf(s[tx * 4 + 1][c]);
        o.z = f2bf(s[tx * 4 + 2][c]);
        o.w = f2bf(s[tx * 4 + 3][c]);
        *(ushort4*)(out + (size_t)(c0 + c) * R + r0 + tx * 4) = o;
    }
}

// ---------------- fused: out = x copy + router logits (f64 accum) ----------------
__global__ __launch_bounds__(256) void k_router_copy(const float* __restrict__ x,
                                                     const float* __restrict__ Wr,
                                                     const float* __restrict__ Wa,
                                                     float* __restrict__ out,
                                                     float* __restrict__ logits,
                                                     float* __restrict__ auxlog) {
    int w = threadIdx.x >> 6, lane = threadIdx.x & 63;
    int row = blockIdx.x * 4 + w;
    const float* xr = x + (size_t)row * D_;
    float* orow = out + (size_t)row * D_;
    double sr = 0.0, sa = 0.0;
#pragma unroll
    for (int it = 0; it < 8; it++) {
        int off = it * 256 + lane * 4;
        float4 xv = *(const float4*)(xr + off);
        float4 rv = *(const float4*)(Wr + off);
        float4 av = *(const float4*)(Wa + off);
        *(float4*)(orow + off) = xv;
        sr += (double)xv.x * rv.x + (double)xv.y * rv.y + (double)xv.z * rv.z + (double)xv.w * rv.w;
        sa += (double)xv.x * av.x + (double)xv.y * av.y + (double)xv.z * av.z + (double)xv.w * av.w;
    }
#pragma unroll
    for (int off = 32; off > 0; off >>= 1) {
        sr += __shfl_down(sr, off);
        sa += __shfl_down(sa, off);
    }
    if (lane == 0) {
        logits[row] = (float)sr;
        auxlog[row] = (float)sa;
    }
}

// ---------------- per-batch top-k via bitonic sort of (value, 4095-idx) keys ----------------
__global__ __launch_bounds__(1024) void k_topk(const float* __restrict__ logits,
                                               int* __restrict__ sel, float* __restrict__ rw,
                                               int* __restrict__ flags) {
    __shared__ unsigned long long keys[S_];
    __shared__ int sarr[SLOTP];
    int b = blockIdx.x, tid = threadIdx.x;
    const float* lg = logits + (size_t)b * S_;
    for (int i = tid; i < S_; i += 1024) {
        unsigned u = __float_as_uint(lg[i]);
        u = (u & 0x80000000u) ? ~u : (u | 0x80000000u);
        keys[i] = ((unsigned long long)u << 32) | (unsigned)(S_ - 1 - i);
    }
    __syncthreads();
    for (int k = 2; k <= S_; k <<= 1) {
        for (int j = k >> 1; j > 0; j >>= 1) {
            for (int s = tid; s < S_ / 2; s += 1024) {
                int i = 2 * s - (s & (j - 1));
                int ixj = i | j;
                bool up = ((i & k) == 0);
                unsigned long long a = keys[i], c = keys[ixj];
                if ((a < c) == up) { keys[i] = c; keys[ixj] = a; }  // descending
            }
            __syncthreads();
        }
    }
    if (tid < KCAP) sarr[tid] = (int)(S_ - 1 - (unsigned)(keys[tid] & 0xFFFFFFFFull));
    __syncthreads();
    if (tid < KCAP) {
        int s = sarr[tid];
        int rank = 0;
        for (int j = 0; j < KCAP; j++) rank += (sarr[j] < s) ? 1 : 0;
        sel[b * SLOTP + rank] = s;
        rw[b * SLOTP + rank] = lg[s];
        flags[s] = 1;
    } else if (tid < SLOTP) {
        sel[b * SLOTP + tid] = 0;
        rw[b * SLOTP + tid] = 0.f;
    }
}

// ---------------- gather selected tokens -> bf16 A [MPAD][D_] ----------------
__global__ __launch_bounds__(256) void k_gather(const float* __restrict__ x,
                                                const int* __restrict__ sel,
                                                unsigned short* __restrict__ Abuf) {
    int row = blockIdx.x;
    int b = row >> 9, slot = row & 511;
    int tid = threadIdx.x;
    unsigned short* dst = Abuf + (size_t)row * D_ + tid * 8;
    if (slot < KCAP) {
        int tok = sel[b * SLOTP + slot];
        const float* src = x + ((size_t)(b * S_ + tok)) * D_ + tid * 8;
        float4 v0 = *(const float4*)(src);
        float4 v1 = *(const float4*)(src + 4);
        union { unsigned short us[8]; uint4 v; } pk;
        pk.us[0] = f2bf(v0.x); pk.us[1] = f2bf(v0.y); pk.us[2] = f2bf(v0.z); pk.us[3] = f2bf(v0.w);
        pk.us[4] = f2bf(v1.x); pk.us[5] = f2bf(v1.y); pk.us[6] = f2bf(v1.z); pk.us[7] = f2bf(v1.w);
        *(uint4*)dst = pk.v;
    } else {
        *(uint4*)dst = make_uint4(0u, 0u, 0u, 0u);
    }
}

// ---------------- fused dual GEMM1: h = silu(A@W1) * (A@W3), bf16 out ----------------
// Tile 128M x 64N dual, BK=64 staged as two BK=32 slices. 32 MFMA per wave per barrier.
__global__ __launch_bounds__(256, 3) void k_gemm1(const unsigned short* __restrict__ A,
                                                  const unsigned short* __restrict__ B1,
                                                  const unsigned short* __restrict__ B2,
                                                  unsigned short* __restrict__ Hbuf) {
    __shared__ unsigned short sA[2][128 * 32];   // 16KB
    __shared__ unsigned short sB1[2][64 * 32];   // 8KB
    __shared__ unsigned short sB2[2][64 * 32];   // 8KB
    const int tid = threadIdx.x;
    const int w = tid >> 6, lane = tid & 63;
    const int n0 = blockIdx.x * 64, m0 = blockIdx.y * 128;
    const int wm = (w >> 1) * 64, wn = (w & 1) * 32;
    const int srow = lane >> 2, skc = (lane & 3) * 8;
    const int lrow = lane & 15, lk = (lane >> 4) * 8;
    float4_t acc1[4][2] = {};
    float4_t acc2[4][2] = {};

    for (int k0 = 0; k0 < D_; k0 += 64) {
#pragma unroll
        for (int ks = 0; ks < 2; ks++) {
            int kk = k0 + ks * 32 + skc;
#pragma unroll
            for (int q = 0; q < 4; q++) {
                int c = w * 4 + q;  // 0..15: 8 chunks A, 4 B1, 4 B2
                if (c < 8) {
                    int row = c * 16 + srow;
                    gload_lds16(A + (size_t)(m0 + row) * D_ + kk, &sA[ks][c * 512]);
                } else if (c < 12) {
                    int s = c - 8, row = s * 16 + srow;
                    gload_lds16(B1 + (size_t)(n0 + row) * D_ + kk, &sB1[ks][s * 512]);
                } else {
                    int s = c - 12, row = s * 16 + srow;
                    gload_lds16(B2 + (size_t)(n0 + row) * D_ + kk, &sB2[ks][s * 512]);
                }
            }
        }
        __builtin_amdgcn_s_waitcnt(0);
        __syncthreads();
#pragma unroll
        for (int ks = 0; ks < 2; ks++) {
            short8 af[4];
#pragma unroll
            for (int i = 0; i < 4; i++)
                af[i] = *(const short8*)(&sA[ks][(wm + i * 16 + lrow) * 32 + lk]);
#pragma unroll
            for (int j = 0; j < 2; j++) {
                short8 bf1 = *(const short8*)(&sB1[ks][(wn + j * 16 + lrow) * 32 + lk]);
                short8 bf2 = *(const short8*)(&sB2[ks][(wn + j * 16 + lrow) * 32 + lk]);
#pragma unroll
                for (int i = 0; i < 4; i++) {
                    acc1[i][j] = __builtin_amdgcn_mfma_f32_16x16x32_bf16(af[i], bf1, acc1[i][j], 0, 0, 0);
                    acc2[i][j] = __builtin_amdgcn_mfma_f32_16x16x32_bf16(af[i], bf2, acc2[i][j], 0, 0, 0);
                }
            }
        }
        __syncthreads();
    }
#pragma unroll
    for (int i = 0; i < 4; i++) {
#pragma unroll
        for (int j = 0; j < 2; j++) {
            int n = n0 + wn + j * 16 + lrow;
#pragma unroll
            for (int r = 0; r < 4; r++) {
                int m = m0 + wm + i * 16 + (lane >> 4) * 4 + r;
                float g1 = acc1[i][j][r];
                float g2 = acc2[i][j][r];
                float hv = (g1 / (1.f + expf(-g1))) * g2;
                Hbuf[(size_t)m * H_ + n] = f2bf(hv);
            }
        }
    }
}

// ---------------- GEMM2 split-K: y = h @ W2, atomic scatter out += rw*y ----------------
// 128x128 tile, BK=64 as two BK=32 slices, splitK=4.
__global__ __launch_bounds__(256, 3) void k_gemm2(const unsigned short* __restrict__ A,
                                                  const unsigned short* __restrict__ Bt,
                                                  const int* __restrict__ sel,
                                                  const float* __restrict__ rw,
                                                  float* __restrict__ out) {
    __shared__ unsigned short sA[2][128 * 32];
    __shared__ unsigned short sB[2][128 * 32];
    const int tid = threadIdx.x;
    const int w = tid >> 6, lane = tid & 63;
    const int n0 = blockIdx.x * 128, m0 = blockIdx.y * 128;
    const int kbeg = blockIdx.z * (H_ / 4), kend = kbeg + H_ / 4;
    const int wm = (w >> 1) * 64, wn = (w & 1) * 64;
    const int srow = lane >> 2, skc = (lane & 3) * 8;
    const int lrow = lane & 15, lk = (lane >> 4) * 8;
    float4_t acc[4][4] = {};

    for (int k0 = kbeg; k0 < kend; k0 += 64) {
#pragma unroll
        for (int ks = 0; ks < 2; ks++) {
            int kk = k0 + ks * 32 + skc;
#pragma unroll
            for (int q = 0; q < 4; q++) {
                int c = w * 4 + q;  // 0..15: 8 chunks A, 8 B
                int sub = c & 7;
                int row = sub * 16 + srow;
                if (c < 8)
                    gload_lds16(A + (size_t)(m0 + row) * H_ + kk, &sA[ks][sub * 512]);
                else
                    gload_lds16(Bt + (size_t)(n0 + row) * H_ + kk, &sB[ks][sub * 512]);
            }
        }
        __builtin_amdgcn_s_waitcnt(0);
        __syncthreads();
#pragma unroll
        for (int ks = 0; ks < 2; ks++) {
            short8 af[4];
#pragma unroll
            for (int i = 0; i < 4; i++)
                af[i] = *(const short8*)(&sA[ks][(wm + i * 16 + lrow) * 32 + lk]);
#pragma unroll
            for (int j = 0; j < 4; j++) {
                short8 bf = *(const short8*)(&sB[ks][(wn + j * 16 + lrow) * 32 + lk]);
#pragma unroll
                for (int i = 0; i < 4; i++)
                    acc[i][j] = __builtin_amdgcn_mfma_f32_16x16x32_bf16(af[i], bf, acc[i][j], 0, 0, 0);
            }
        }
        __syncthreads();
    }
#pragma unroll
    for (int i = 0; i < 4; i++) {
#pragma unroll
        for (int r = 0; r < 4; r++) {
            int m = m0 + wm + i * 16 + (lane >> 4) * 4 + r;
            int b = m >> 9, slot = m & 511;
            if (slot < KCAP) {
                int tok = sel[b * SLOTP + slot];
                float wgt = rw[b * SLOTP + slot];
                float* orow = out + ((size_t)(b * S_ + tok)) * D_;
#pragma unroll
                for (int j = 0; j < 4; j++) {
                    int n = n0 + wn + j * 16 + lrow;
                    atomicAdd(orow + n, wgt * acc[i][j][r]);
                }
            }
        }
    }
}

// ---------------- aux BCE loss (reproduces reference's tgt-indexing quirk) ----------------
__global__ __launch_bounds__(256) void k_aux(const float* __restrict__ auxlog,
                                             const int* __restrict__ flags,
                                             float* __restrict__ auxout) {
    int i = blockIdx.x * 256 + threadIdx.x;
    float z = auxlog[i];
    float p = 1.f / (1.f + expf(-z));
    p = fminf(fmaxf(p, 1e-7f), 1.f - 1e-7f);
    int tgt = (i < S_) ? flags[i] : 0;
    float term = tgt ? logf(p) : log1pf(-p);
#pragma unroll
    for (int off = 32; off > 0; off >>= 1) term += __shfl_down(term, off);
    __shared__ float red[4];
    int w = threadIdx.x >> 6, lane = threadIdx.x & 63;
    if (lane == 0) red[w] = term;
    __syncthreads();
    if (threadIdx.x == 0) {
        float s = red[0] + red[1] + red[2] + red[3];
        atomicAdd(auxout, -s * (1.f / 16384.f));
    }
}

extern "C" void kernel_launch(void* const* d_in, const int* in_sizes, int n_in,
                              void* d_out, int out_size, void* d_ws, size_t ws_size,
                              hipStream_t stream) {
    const float* x  = (const float*)d_in[0];
    const float* Wr = (const float*)d_in[1];
    const float* Wa = (const float*)d_in[2];
    const float* W1 = (const float*)d_in[3];
    const float* W2 = (const float*)d_in[4];  // dict order: W2 before W3
    const float* W3 = (const float*)d_in[5];
    float* out = (float*)d_out;

    char* ws = (char*)d_ws;
    unsigned short* WTa  = (unsigned short*)(ws);                // 32MB: W1t, later W2t
    unsigned short* WTb  = (unsigned short*)(ws + 33554432ull);  // 32MB: W3t
    unsigned short* Abuf = (unsigned short*)(ws + 67108864ull);  // 8MB:  gathered tokens bf16
    unsigned short* Hbuf = (unsigned short*)(ws + 75497472ull);  // 32MB: SwiGLU hidden bf16
    float* logits = (float*)(ws + 109051904ull);                 // 64KB
    float* auxlog = (float*)(ws + 109117440ull);                 // 64KB
    int*   sel    = (int*)(ws + 109182976ull);                   // 8KB
    float* rwbuf  = (float*)(ws + 109191168ull);                 // 8KB
    int*   flags  = (int*)(ws + 109199360ull);                   // 16KB
    if (ws_size < 109215744ull) return;

    hipMemsetAsync(flags, 0, S_ * sizeof(int), stream);
    hipMemsetAsync(out + (size_t)B_ * S_ * D_, 0, sizeof(float), stream);

    k_transpose_bf16<<<dim3(D_ / 64, H_ / 64), 256, 0, stream>>>(W1, WTa, D_, H_);
    k_transpose_bf16<<<dim3(D_ / 64, H_ / 64), 256, 0, stream>>>(W3, WTb, D_, H_);
    k_router_copy<<<4096, 256, 0, stream>>>(x, Wr, Wa, out, logits, auxlog);
    k_topk<<<4, 1024, 0, stream>>>(logits, sel, rwbuf, flags);
    k_gather<<<MPAD, 256, 0, stream>>>(x, sel, Abuf);
    k_gemm1<<<dim3(H_ / 64, MPAD / 128), 256, 0, stream>>>(Abuf, WTa, WTb, Hbuf);
    k_transpose_bf16<<<dim3(H_ / 64, D_ / 64), 256, 0, stream>>>(W2, WTa, H_, D_);
    k_gemm2<<<dim3(D_ / 128, MPAD / 128, 4), 256, 0, stream>>>(Hbuf, WTa, sel, rwbuf, out);
    k_aux<<<64, 256, 0, stream>>>(auxlog, flags, out + (size_t)B_ * S_ * D_);
}